// Round 19
// baseline (27.166 us; speedup 1.0000x reference)
//
#include <hip/hip_runtime.h>

#define IMH 384
#define IMW 384
#define OH 378
#define OW 378
#define NB 64
#define SROWS 21
#define INROWS 27          // computed rows per strip (27 = 21 + 6)
#define NSTRIP 18          // 18*21 = 378 exactly
#define BLOCK 256          // 4 waves = 16 DPP groups of 16 lanes
#define GSTRIDE 26         // output cols per group (13 lanes x 2 cols)
#define NPAIR 14           // staged row-pairs (28 rows; row 27 = clamped pad)
#define SLOTF 512          // floats per row: 384 data + 128 pad (2048 B)
#define NBLK (NSTRIP * NB) // 1152 partials

// Round 28 (FINAL): R27 confirmed V24+finalize levers null (26.5 vs R22's
// 26.1; V24 sign-negative - dependent f2add at DPP chain head). This is
// R22 VERBATIM (the measured optimum across 18 rounds) + the isolated-safe
// 256-thread finalize. Session ledger:
//   116.7 -> 26.1 us. Positive: occupancy (6,6), linearized decode,
//   global_load_lds DMA ring w/ counted vmcnt (never 0 mid-loop),
//   pair-phase software pipeline, sum-domain SSIM algebra.
//   Null: wave count, scheduler freedom, forced reg prefetch, de-phased
//   wave-private rings, full-strip prefetch, V24, barriers (-0.3us only).
//   POISON (banned): fused-finalize tail -> allocator drops to VGPR 40-52
//   and remats the pipeline into serial LDS re-reads (3-for-3 collapses).
// NOT a roofline: VALUBusy ~35%, HBM ~15%. Structural plateau - residual
// is distributed phase-boundary latency; next lever would be a 4-col/lane
// retile with cross-row window sums (high risk, est -25% VALU).

template <int CTRL>
__device__ __forceinline__ float dpp_sh(float v) {
    return __int_as_float(__builtin_amdgcn_update_dpp(
        0, __float_as_int(v), CTRL, 0xf, 0xf, true));
}

__device__ __forceinline__ float2 f2add(float2 a, float2 b) { return make_float2(a.x + b.x, a.y + b.y); }
__device__ __forceinline__ float2 f2sub(float2 a, float2 b) { return make_float2(a.x - b.x, a.y - b.y); }
__device__ __forceinline__ float2 f2mul(float2 a, float2 b) { return make_float2(a.x * b.x, a.y * b.y); }
__device__ __forceinline__ float2 f2fma(float2 a, float2 b, float2 c) {
    return make_float2(fmaf(a.x, b.x, c.x), fmaf(a.y, b.y, c.y));
}
__device__ __forceinline__ float2 f2fnma(float2 a, float2 b, float2 c) {  // c - a*b
    return make_float2(fmaf(-a.x, b.x, c.x), fmaf(-a.y, b.y, c.y));
}
__device__ __forceinline__ float2 f2fms(float2 a, float s, float2 c) {    // a*s - c
    return make_float2(fmaf(a.x, s, -c.x), fmaf(a.y, s, -c.y));
}
__device__ __forceinline__ float2 f2s(float s) { return make_float2(s, s); }

// async global->LDS DMA, 16B per lane; dest = wave-uniform base + lane*16B
__device__ __forceinline__ void stage16(const float* g, float* l) {
    __builtin_amdgcn_global_load_lds(
        (const __attribute__((address_space(1))) uint32_t*)(g),
        (__attribute__((address_space(3))) uint32_t*)(l),
        16, 0, 0);
}

#define WAITV(n) asm volatile("s_waitcnt vmcnt(" #n ")" ::: "memory")
#define RAWBAR() asm volatile("s_barrier" ::: "memory")

__global__ __launch_bounds__(BLOCK)
__attribute__((amdgpu_waves_per_eu(6, 6)))
void ssim_kernel(
    const float* __restrict__ X, const float* __restrict__ Y,
    const float* __restrict__ data_range, float* __restrict__ partials)
{
    const int tid   = threadIdx.x;
    const int g     = tid >> 4;               // DPP group 0..15
    const int j     = tid & 15;               // lane within group
    const int strip = blockIdx.x;
    const int b     = blockIdx.y;
    const int y0    = strip * SROWS;          // <= 357

    // pair-slot ring: [pairslot][row-in-pair][floats]; 16 KB per tensor
    __shared__ float sX[4][2][SLOTF];
    __shared__ float sY[4][2][SLOTF];

    // ---- staging role: wv0=X-lo wv1=X-hi wv2=Y-lo wv3=Y-hi ----
    const int wv   = tid >> 6;
    const int ln   = tid & 63;
    const bool isX = (wv < 2);
    const int half = wv & 1;                  // 0: floats 0..255, 1: 256..511
    const int foff = half * 256 + ln * 4;     // float col of this lane's 16B
    const int fcl  = min(foff, IMW - 4);      // pad lanes re-read last 16B
    const float* __restrict__ gstg =
        (isX ? X : Y) + b * (IMH * IMW) + y0 * IMW + fcl;
    const float* __restrict__ gstg27 =        // row 27, clamped (strip 17)
        (isX ? X : Y) + b * (IMH * IMW) + min(y0 + 27, IMH - 1) * IMW + fcl;
    float* const lbase = (isX ? &sX[0][0][0] : &sY[0][0][0]) + foff;

    // compute-side column mapping
    const int ce  = g * GSTRIDE + 2 * j;      // lane's even column (global)
    const int cin = min(ce, IMW - 2);         // clamped, even -> 8B aligned
    const float2 vmask = make_float2(
        ((j <= 12) && (ce     < OW)) ? 1.f : 0.f,
        ((j <= 12) && (ce + 1 < OW)) ? 1.f : 0.f);

    // sum-domain constants (scale 49^4 cancels in the SSIM ratio)
    const float L   = data_range[b];
    const float c1s = (0.49f * L) * (0.49f * L);      // 49^2 * C1
    const float c2s = (1.47f * L) * (1.47f * L);      // 49^2 * C2
    const float k1  = 49.0f / 48.0f;                  // covn
    const float k2  = 49.0f / 24.0f;                  // 2*covn
    asm volatile("" :: "v"(c1s), "v"(c2s));
    __builtin_amdgcn_sched_barrier(0);

    // ---- prologue: DMA pairs 0..3 (8 instrs/wave) ----
    #pragma unroll
    for (int q = 0; q < 4; ++q) {
        stage16(gstg + (2 * q) * IMW,     lbase + (2 * q + 0) * SLOTF);
        stage16(gstg + (2 * q + 1) * IMW, lbase + (2 * q + 1) * SLOTF);
    }
    WAITV(6);                                 // pair 0 complete (own)
    RAWBAR();                                 // all waves' pair 0 complete
    float2 cx0 = *(const float2*)&sX[0][0][cin];
    float2 cx1 = *(const float2*)&sX[0][1][cin];
    float2 cy0 = *(const float2*)&sY[0][0][cin];
    float2 cy1 = *(const float2*)&sY[0][1][cin];

    float2 xh[7], yh[7];
    #pragma unroll
    for (int k = 0; k < 7; ++k) { xh[k] = f2s(0.f); yh[k] = f2s(0.f); }
    float2 V0 = f2s(0.f), V1 = f2s(0.f), V2 = f2s(0.f),
           V3 = f2s(0.f), V4 = f2s(0.f);
    float2 ls2 = f2s(0.f);

    auto rowcompute = [&](int r, float2 x, float2 y) {
        const int ks = r % 7;                          // static after unroll
        const float2 xo = xh[ks], yo = yh[ks];
        V0 = f2add(V0, f2sub(x, xo));
        V1 = f2add(V1, f2sub(y, yo));
        V2 = f2fma(x, x, V2);  V2 = f2fnma(xo, xo, V2);
        V3 = f2fma(x, y, V3);  V3 = f2fnma(xo, yo, V3);
        V4 = f2fma(y, y, V4);  V4 = f2fnma(yo, yo, V4);
        xh[ks] = x; yh[ks] = y;

        if (r >= 6) {   // output row o = y0+r-6 < OH by tiling
            const float2 Vv[5] = {V0, V1, V2, V3, V4};
            float Se[5], So[5];
            #pragma unroll
            for (int q = 0; q < 5; ++q) {
                const float e  = Vv[q].x;
                const float o  = Vv[q].y;
                const float pp = e + o;
                float B = pp + dpp_sh<0x101>(pp);      // pp(l)+pp(l+1)
                float C = B + dpp_sh<0x102>(B);        // pp(l..l+3)
                Se[q] = C - dpp_sh<0x103>(o);          // cols 2l..2l+6
                So[q] = C - e;                         // cols 2l+1..2l+7
            }
            const float2 S0 = make_float2(Se[0], So[0]);
            const float2 S1 = make_float2(Se[1], So[1]);
            const float2 S2 = make_float2(Se[2], So[2]);
            const float2 S3 = make_float2(Se[3], So[3]);
            const float2 S4 = make_float2(Se[4], So[4]);

            // sum-domain SSIM (R21-R27-verified exact: absmax 0.0)
            float2 P  = f2mul(S0, S1);
            float2 q1 = f2mul(S1, S1);
            float2 QQ = f2fma(S0, S0, q1);
            float2 N1 = f2fma(f2s(2.f), P, f2s(c1s));
            float2 D1 = f2add(QQ, f2s(c1s));
            float2 w  = f2fms(S3, 49.0f, P);           // 49*S3 - S0*S1
            float2 N2 = f2fma(f2s(k2), w, f2s(c2s));
            float2 t  = f2add(S2, S4);
            float2 u  = f2fms(t, 49.0f, QQ);           // 49*(S2+S4) - QQ
            float2 D2 = f2fma(f2s(k1), u, f2s(c2s));
            float2 num = f2mul(N1, N2);
            float2 den = f2mul(D1, D2);
            const float rdd = __builtin_amdgcn_rcpf(den.x * den.y);
            float2 s2 = make_float2(num.x * den.y * rdd,
                                    num.y * den.x * rdd);
            ls2 = f2fma(s2, vmask, ls2);
        }
    };

    static_assert(INROWS == 27 && NPAIR == 14, "ladder");

    #pragma unroll
    for (int p = 1; p < NPAIR; ++p) {
        // wait own pair-p DMAs (outstanding before: pairs p..p+2 = 6)
        if      (p <= 11) WAITV(4);
        else if (p == 12) WAITV(2);
        else              WAITV(0);
        RAWBAR();                             // all waves' pair p complete

        // read pair p into next-regs (latency hides under pair p-1 compute)
        const int sl = p & 3;
        float2 nx0 = *(const float2*)&sX[sl][0][cin];
        float2 nx1 = *(const float2*)&sX[sl][1][cin];
        float2 ny0 = *(const float2*)&sY[sl][0][cin];
        float2 ny1 = *(const float2*)&sY[sl][1][cin];

        // compute pair p-1 (lgkm-drains cur's reads from slot (p-1)&3)
        rowcompute(2 * (p - 1),     cx0, cy0);
        rowcompute(2 * (p - 1) + 1, cx1, cy1);

        // issue DMA pair p+3 into slot (p+3)&3 == (p-1)&3: its previous
        // reads were consumed just above -> race-free by program order.
        if (p + 3 < NPAIR) {
            const int q = p + 3;
            const float* s1 = (q == 13) ? gstg27 : gstg + (2 * q + 1) * IMW;
            stage16(gstg + (2 * q) * IMW, lbase + ((q & 3) * 2 + 0) * SLOTF);
            stage16(s1,                   lbase + ((q & 3) * 2 + 1) * SLOTF);
        }

        cx0 = nx0; cx1 = nx1; cy0 = ny0; cy1 = ny1;
    }

    // epilogue: pair 13 = row 26 (row 27 is clamped pad, never computed)
    rowcompute(26, cx0, cy0);

    // ---- block reduction -> plain store (reuse sX; loop fully done) ----
    float lsum = ls2.x + ls2.y;
    #pragma unroll
    for (int off = 32; off > 0; off >>= 1)
        lsum += __shfl_down(lsum, off, 64);
    __syncthreads();
    if ((tid & 63) == 0) sX[0][0][tid >> 6] = lsum;
    __syncthreads();
    if (tid == 0) {
        partials[b * NSTRIP + strip] =
            sX[0][0][0] + sX[0][0][1] + sX[0][0][2] + sX[0][0][3];
    }
}

__global__ void finalize_kernel(const float* __restrict__ partials,
                                float* __restrict__ out)
{
    // 256 threads reduce NBLK = 1152 partials (4-5 strided loads each)
    const int tid = threadIdx.x;
    float v = 0.f;
    for (int k = tid; k < NBLK; k += 256)
        v += partials[k];
    #pragma unroll
    for (int off = 32; off > 0; off >>= 1)
        v += __shfl_down(v, off, 64);
    __shared__ float red[4];
    if ((tid & 63) == 0) red[tid >> 6] = v;
    __syncthreads();
    if (tid == 0)
        out[0] = 1.0f - (red[0] + red[1] + red[2] + red[3])
                        * (1.0f / (float)(NB * OH * OW));
}

extern "C" void kernel_launch(void* const* d_in, const int* in_sizes, int n_in,
                              void* d_out, int out_size, void* d_ws, size_t ws_size,
                              hipStream_t stream) {
    const float* X  = (const float*)d_in[0];
    const float* Y  = (const float*)d_in[1];
    const float* dr = (const float*)d_in[2];
    float* out = (float*)d_out;
    float* partials = (float*)d_ws;           // NBLK floats, fully written

    dim3 grid(NSTRIP, NB);      // 18 x 64 = 1152 blocks
    dim3 block(BLOCK);          // 256 threads = 4 waves
    ssim_kernel<<<grid, block, 0, stream>>>(X, Y, dr, partials);
    finalize_kernel<<<1, 256, 0, stream>>>(partials, out);
}

// Round 22
// 26.090 us; speedup vs baseline: 1.0412x; 1.0412x over previous
//
#include <hip/hip_runtime.h>

#define IMH 384
#define IMW 384
#define OH 378
#define OW 378
#define NB 64
#define SROWS 21
#define INROWS 27          // computed rows per strip (27 = 21 + 6)
#define NSTRIP 18          // 18*21 = 378 exactly
#define BLOCK 256          // 4 waves = 16 DPP groups of 16 lanes
#define GSTRIDE 26         // output cols per group (13 lanes x 2 cols)
#define NPAIR 14           // staged row-pairs (28 rows; row 27 = clamped pad)
#define SLOTF 512          // floats per row: 384 data + 128 pad (2048 B)

// Round 31 = third submission of the R22-verbatim optimum. R29 and R30
// both died with UnresponsiveContainer BEFORE job submission — same dead
// container instance (strong-small-robust-vigor) both times; Round 6 had
// the identical failure mode and recovered on resubmit. The kernel itself
// has run cleanly 4x (R13 = 26.1us; R25/R27/R28 variants 26.5-27.2, all
// within the ±1us noise band with this exact main kernel).
//
// Session ledger (116.7 -> 26.1us, 4.5x):
//   Working levers: (6,6) occupancy pin, global_load_lds DMA ring with
//   counted vmcnt (never 0 mid-loop), pair-phase software pipeline
//   (ds_read one pair ahead of compute), sum-domain SSIM algebra.
//   Null: wave count, scheduler freedom, forced reg prefetch, de-phased
//   wave-private rings, full-strip prefetch, V24 merge, barrier count.
//   POISON (banned): fused-finalize tail -> allocator collapse to VGPR
//   40-52 with LDS-remat of the pipeline (3-for-3 reproductions).
// NOT a roofline: VALUBusy ~35%, HBM ~15% — structural phase-boundary
// latency plateau; remaining untried lever (4-col/lane retile) has
// negative EV against this session's ground-up-rewrite track record.

template <int CTRL>
__device__ __forceinline__ float dpp_sh(float v) {
    return __int_as_float(__builtin_amdgcn_update_dpp(
        0, __float_as_int(v), CTRL, 0xf, 0xf, true));
}

__device__ __forceinline__ float2 f2add(float2 a, float2 b) { return make_float2(a.x + b.x, a.y + b.y); }
__device__ __forceinline__ float2 f2sub(float2 a, float2 b) { return make_float2(a.x - b.x, a.y - b.y); }
__device__ __forceinline__ float2 f2mul(float2 a, float2 b) { return make_float2(a.x * b.x, a.y * b.y); }
__device__ __forceinline__ float2 f2fma(float2 a, float2 b, float2 c) {
    return make_float2(fmaf(a.x, b.x, c.x), fmaf(a.y, b.y, c.y));
}
__device__ __forceinline__ float2 f2fnma(float2 a, float2 b, float2 c) {  // c - a*b
    return make_float2(fmaf(-a.x, b.x, c.x), fmaf(-a.y, b.y, c.y));
}
__device__ __forceinline__ float2 f2fms(float2 a, float s, float2 c) {    // a*s - c
    return make_float2(fmaf(a.x, s, -c.x), fmaf(a.y, s, -c.y));
}
__device__ __forceinline__ float2 f2s(float s) { return make_float2(s, s); }

// async global->LDS DMA, 16B per lane; dest = wave-uniform base + lane*16B
__device__ __forceinline__ void stage16(const float* g, float* l) {
    __builtin_amdgcn_global_load_lds(
        (const __attribute__((address_space(1))) uint32_t*)(g),
        (__attribute__((address_space(3))) uint32_t*)(l),
        16, 0, 0);
}

#define WAITV(n) asm volatile("s_waitcnt vmcnt(" #n ")" ::: "memory")
#define RAWBAR() asm volatile("s_barrier" ::: "memory")

__global__ __launch_bounds__(BLOCK)
__attribute__((amdgpu_waves_per_eu(6, 6)))
void ssim_kernel(
    const float* __restrict__ X, const float* __restrict__ Y,
    const float* __restrict__ data_range, float* __restrict__ partials)
{
    const int tid   = threadIdx.x;
    const int g     = tid >> 4;               // DPP group 0..15
    const int j     = tid & 15;               // lane within group
    const int strip = blockIdx.x;
    const int b     = blockIdx.y;
    const int y0    = strip * SROWS;          // <= 357

    // pair-slot ring: [pairslot][row-in-pair][floats]; 16 KB per tensor
    __shared__ float sX[4][2][SLOTF];
    __shared__ float sY[4][2][SLOTF];

    // ---- staging role: wv0=X-lo wv1=X-hi wv2=Y-lo wv3=Y-hi ----
    const int wv   = tid >> 6;
    const int ln   = tid & 63;
    const bool isX = (wv < 2);
    const int half = wv & 1;                  // 0: floats 0..255, 1: 256..511
    const int foff = half * 256 + ln * 4;     // float col of this lane's 16B
    const int fcl  = min(foff, IMW - 4);      // pad lanes re-read last 16B
    const float* __restrict__ gstg =
        (isX ? X : Y) + b * (IMH * IMW) + y0 * IMW + fcl;
    const float* __restrict__ gstg27 =        // row 27, clamped (strip 17)
        (isX ? X : Y) + b * (IMH * IMW) + min(y0 + 27, IMH - 1) * IMW + fcl;
    float* const lbase = (isX ? &sX[0][0][0] : &sY[0][0][0]) + foff;

    // compute-side column mapping
    const int ce  = g * GSTRIDE + 2 * j;      // lane's even column (global)
    const int cin = min(ce, IMW - 2);         // clamped, even -> 8B aligned
    const float2 vmask = make_float2(
        ((j <= 12) && (ce     < OW)) ? 1.f : 0.f,
        ((j <= 12) && (ce + 1 < OW)) ? 1.f : 0.f);

    // sum-domain constants (scale 49^4 cancels in the SSIM ratio)
    const float L   = data_range[b];
    const float c1s = (0.49f * L) * (0.49f * L);      // 49^2 * C1
    const float c2s = (1.47f * L) * (1.47f * L);      // 49^2 * C2
    const float k1  = 49.0f / 48.0f;                  // covn
    const float k2  = 49.0f / 24.0f;                  // 2*covn
    asm volatile("" :: "v"(c1s), "v"(c2s));
    __builtin_amdgcn_sched_barrier(0);

    // ---- prologue: DMA pairs 0..3 (8 instrs/wave) ----
    #pragma unroll
    for (int q = 0; q < 4; ++q) {
        stage16(gstg + (2 * q) * IMW,     lbase + (2 * q + 0) * SLOTF);
        stage16(gstg + (2 * q + 1) * IMW, lbase + (2 * q + 1) * SLOTF);
    }
    WAITV(6);                                 // pair 0 complete (own)
    RAWBAR();                                 // all waves' pair 0 complete
    float2 cx0 = *(const float2*)&sX[0][0][cin];
    float2 cx1 = *(const float2*)&sX[0][1][cin];
    float2 cy0 = *(const float2*)&sY[0][0][cin];
    float2 cy1 = *(const float2*)&sY[0][1][cin];

    float2 xh[7], yh[7];
    #pragma unroll
    for (int k = 0; k < 7; ++k) { xh[k] = f2s(0.f); yh[k] = f2s(0.f); }
    float2 V0 = f2s(0.f), V1 = f2s(0.f), V2 = f2s(0.f),
           V3 = f2s(0.f), V4 = f2s(0.f);
    float2 ls2 = f2s(0.f);

    auto rowcompute = [&](int r, float2 x, float2 y) {
        const int ks = r % 7;                          // static after unroll
        const float2 xo = xh[ks], yo = yh[ks];
        V0 = f2add(V0, f2sub(x, xo));
        V1 = f2add(V1, f2sub(y, yo));
        V2 = f2fma(x, x, V2);  V2 = f2fnma(xo, xo, V2);
        V3 = f2fma(x, y, V3);  V3 = f2fnma(xo, yo, V3);
        V4 = f2fma(y, y, V4);  V4 = f2fnma(yo, yo, V4);
        xh[ks] = x; yh[ks] = y;

        if (r >= 6) {   // output row o = y0+r-6 < OH by tiling
            const float2 Vv[5] = {V0, V1, V2, V3, V4};
            float Se[5], So[5];
            #pragma unroll
            for (int q = 0; q < 5; ++q) {
                const float e  = Vv[q].x;
                const float o  = Vv[q].y;
                const float pp = e + o;
                float B = pp + dpp_sh<0x101>(pp);      // pp(l)+pp(l+1)
                float C = B + dpp_sh<0x102>(B);        // pp(l..l+3)
                Se[q] = C - dpp_sh<0x103>(o);          // cols 2l..2l+6
                So[q] = C - e;                         // cols 2l+1..2l+7
            }
            const float2 S0 = make_float2(Se[0], So[0]);
            const float2 S1 = make_float2(Se[1], So[1]);
            const float2 S2 = make_float2(Se[2], So[2]);
            const float2 S3 = make_float2(Se[3], So[3]);
            const float2 S4 = make_float2(Se[4], So[4]);

            // sum-domain SSIM (R21-R28-verified exact: absmax 0.0)
            float2 P  = f2mul(S0, S1);
            float2 q1 = f2mul(S1, S1);
            float2 QQ = f2fma(S0, S0, q1);
            float2 N1 = f2fma(f2s(2.f), P, f2s(c1s));
            float2 D1 = f2add(QQ, f2s(c1s));
            float2 w  = f2fms(S3, 49.0f, P);           // 49*S3 - S0*S1
            float2 N2 = f2fma(f2s(k2), w, f2s(c2s));
            float2 t  = f2add(S2, S4);
            float2 u  = f2fms(t, 49.0f, QQ);           // 49*(S2+S4) - QQ
            float2 D2 = f2fma(f2s(k1), u, f2s(c2s));
            float2 num = f2mul(N1, N2);
            float2 den = f2mul(D1, D2);
            const float rdd = __builtin_amdgcn_rcpf(den.x * den.y);
            float2 s2 = make_float2(num.x * den.y * rdd,
                                    num.y * den.x * rdd);
            ls2 = f2fma(s2, vmask, ls2);
        }
    };

    static_assert(INROWS == 27 && NPAIR == 14, "ladder");

    #pragma unroll
    for (int p = 1; p < NPAIR; ++p) {
        // wait own pair-p DMAs (outstanding before: pairs p..p+2 = 6)
        if      (p <= 11) WAITV(4);
        else if (p == 12) WAITV(2);
        else              WAITV(0);
        RAWBAR();                             // all waves' pair p complete

        // read pair p into next-regs (latency hides under pair p-1 compute)
        const int sl = p & 3;
        float2 nx0 = *(const float2*)&sX[sl][0][cin];
        float2 nx1 = *(const float2*)&sX[sl][1][cin];
        float2 ny0 = *(const float2*)&sY[sl][0][cin];
        float2 ny1 = *(const float2*)&sY[sl][1][cin];

        // compute pair p-1 (lgkm-drains cur's reads from slot (p-1)&3)
        rowcompute(2 * (p - 1),     cx0, cy0);
        rowcompute(2 * (p - 1) + 1, cx1, cy1);

        // issue DMA pair p+3 into slot (p+3)&3 == (p-1)&3: its previous
        // reads were consumed just above -> race-free by program order.
        if (p + 3 < NPAIR) {
            const int q = p + 3;
            const float* s1 = (q == 13) ? gstg27 : gstg + (2 * q + 1) * IMW;
            stage16(gstg + (2 * q) * IMW, lbase + ((q & 3) * 2 + 0) * SLOTF);
            stage16(s1,                   lbase + ((q & 3) * 2 + 1) * SLOTF);
        }

        cx0 = nx0; cx1 = nx1; cy0 = ny0; cy1 = ny1;
    }

    // epilogue: pair 13 = row 26 (row 27 is clamped pad, never computed)
    rowcompute(26, cx0, cy0);

    // ---- block reduction -> plain store (reuse sX; loop fully done) ----
    float lsum = ls2.x + ls2.y;
    #pragma unroll
    for (int off = 32; off > 0; off >>= 1)
        lsum += __shfl_down(lsum, off, 64);
    __syncthreads();
    if ((tid & 63) == 0) sX[0][0][tid >> 6] = lsum;
    __syncthreads();
    if (tid == 0) {
        partials[b * NSTRIP + strip] =
            sX[0][0][0] + sX[0][0][1] + sX[0][0][2] + sX[0][0][3];
    }
}

__global__ void finalize_kernel(const float* __restrict__ partials,
                                float* __restrict__ out)
{
    float v = 0.f;
    #pragma unroll
    for (int k = 0; k < NSTRIP; ++k)
        v += partials[threadIdx.x + 64 * k];
    #pragma unroll
    for (int off = 32; off > 0; off >>= 1)
        v += __shfl_down(v, off, 64);
    if (threadIdx.x == 0)
        out[0] = 1.0f - v * (1.0f / (float)(NB * OH * OW));
}

extern "C" void kernel_launch(void* const* d_in, const int* in_sizes, int n_in,
                              void* d_out, int out_size, void* d_ws, size_t ws_size,
                              hipStream_t stream) {
    const float* X  = (const float*)d_in[0];
    const float* Y  = (const float*)d_in[1];
    const float* dr = (const float*)d_in[2];
    float* out = (float*)d_out;
    float* partials = (float*)d_ws;           // NSTRIP*NB floats, fully written

    dim3 grid(NSTRIP, NB);      // 18 x 64 = 1152 blocks
    dim3 block(BLOCK);          // 256 threads = 4 waves
    ssim_kernel<<<grid, block, 0, stream>>>(X, Y, dr, partials);
    finalize_kernel<<<1, 64, 0, stream>>>(partials, out);
}